// Round 16
// baseline (148.425 us; speedup 1.0000x reference)
//
#include <hip/hip_runtime.h>

// Correlation via bf16 MFMA banded Gram.
// out[b, dyp*21+k, y, x] = (1/256) * sum_c in1[b,c,y,x] * in2[b,c,y+2(dyp-10), x+2(k-10)]
// Layouts (workspace): Ag/Bg[b*64+y][par*48+col][c] bf16, x = 2*col+par.
//
// R22 = R15/R18 frame with the scr epilogue DELETED: each lane stores its 36
// acc elements directly (predicated k<21), addresses (k,xe) from the MFMA C
// layout. Rationale: 6 falsified levers left the epilogue chain (~140 LDS ops
// + 34 stores per wave-round, serial) as the largest unprobed cost, and scr's
// LDS is what pinned 2 blocks/CU all session. Without scr: LDS = Bsh only
// (24,576B) -> 4 blocks/CU; inner loop compiled to 60 VGPR in R15, so
// launch_bounds(512,4) (cap 64) permits 8 waves/SIMD = 32 waves/CU capacity.
// Store-merge: line gets 8 dwords from one wave's clustered epilogue + 8 from
// the launch-adjacent par-sibling (R18 bit0 mapping) -> L2 byte-enable merge.
// Canaries: WRITE >80MB = merge fail/spill; FETCH +40MB = partial-line RMW.
// Harness floor: 2x ~43us fillBufferAligned (256MiB ws poison), untouchable.

typedef short bf16x8 __attribute__((ext_vector_type(8)));
typedef float f32x4  __attribute__((ext_vector_type(4)));

#define PLANE 24576         // shorts per (b,y) plane: 96 rows * 256 c
#define ST    40            // prepass LDS row stride (shorts)

__device__ __forceinline__ short f2bf(float f) {
    union { float f; unsigned u; } x; x.f = f;
    const unsigned u = x.u;
    return (short)((u + 0x7fffu + ((u >> 16) & 1u)) >> 16);
}

// ---------- prepass: fp32 [b][c][y][x] -> bf16 [b*64+y][par*48+col][c] ----------
__global__ __launch_bounds__(512)
void corr_prepass(const float* __restrict__ in1, const float* __restrict__ in2,
                  short* __restrict__ dstA, short* __restrict__ dstB) {
    const int bid = blockIdx.x;
    const int sel = bid >> 8;
    const int r   = bid & 255;
    const int b   = r >> 6;
    const int yt  = (r >> 3) & 7;
    const int ct  = r & 7;
    const int c0 = ct * 32, y0 = yt * 8;
    const float* src = sel ? in2 : in1;
    short* dst = sel ? dstB : dstA;

    __shared__ __align__(16) short T[768 * ST];   // [xx = yy*96+x][32c], 61.4 KB
    const int tid = threadIdx.x;

#pragma unroll
    for (int it = 0; it < 2; ++it) {
        const int d = it * 512 + tid;            // [0,1024), use d<768
        if (d < 768) {
            const int g = d / 192;
            const int f = d - g * 192;
            float4 v[8];
#pragma unroll
            for (int j = 0; j < 8; ++j) {
                const int c = c0 + g * 8 + j;
                v[j] = *(const float4*)(src + ((size_t)(b * 256 + c) * 64 + y0) * 96 + 4 * f);
            }
            bf16x8 w0, w1, w2, w3;
#pragma unroll
            for (int j = 0; j < 8; ++j) {
                w0[j] = f2bf(v[j].x); w1[j] = f2bf(v[j].y);
                w2[j] = f2bf(v[j].z); w3[j] = f2bf(v[j].w);
            }
            const int perm = ((g ^ (f & 3)) * 8);
            const int base = 4 * f * ST + perm;
            *(bf16x8*)&T[base]          = w0;
            *(bf16x8*)&T[base + ST]     = w1;
            *(bf16x8*)&T[base + 2*ST]   = w2;
            *(bf16x8*)&T[base + 3*ST]   = w3;
        }
    }
    __syncthreads();

#pragma unroll
    for (int it = 0; it < 6; ++it) {
        const int D  = it * 512 + tid;           // [0,3072)
        const int Rl = D >> 2, gp = D & 3;
        const int yy  = Rl / 96;
        const int rl  = Rl - yy * 96;
        const int par = rl / 48;
        const int col = rl - par * 48;
        const int x   = 2 * col + par;
        const int xx  = yy * 96 + x;
        const int perm = ((gp ^ ((xx >> 2) & 3)) * 8);
        const bf16x8 w = *(const bf16x8*)&T[xx * ST + perm];
        const size_t Rg = (size_t)(b * 64 + y0 + yy) * 96 + par * 48 + col;
        *(bf16x8*)(dst + Rg * 256 + c0 + gp * 8) = w;
    }
}

// ---------- main kernel: 512 thr = 8 waves = 8 slots, single par ----------
// Barrier-free rounds; NO scr: direct per-lane predicated stores.
__global__ __launch_bounds__(512, 4)
void corr_mfma(const short* __restrict__ Ag, const short* __restrict__ Bg,
               float* __restrict__ out) {
    // XCD chunk = (b, y2-half); par in dispatch bit0 (par-siblings adjacent ->
    // their interleaved half-line stores merge in the same L2 window).
    const int bhw = blockIdx.x;                  // [0,512)
    const int bid = ((bhw & 7) << 6) | (bhw >> 3);
    const int xcd = bid >> 6;
    const int b   = xcd >> 1;
    const int yhi = xcd & 1;
    const int inner = bid & 63;
    const int par = inner & 1;
    const int y2  = (yhi << 5) | (inner >> 1);
    const int by2 = b * 64 + y2;

    const int tid  = threadIdx.x;
    const int lane = tid & 63, slot = tid >> 6;  // slot in [0,8)
    const int n    = lane & 15, q = lane >> 4;

    __shared__ __align__(16) short Bsh[48 * 256];    // 24576 B, XOR-swizzled rows

    // stage B(b,y2) par-half ONCE (swizzle: short_idx ^= (row&7)<<3)
    {
        const short* src = Bg + (size_t)by2 * PLANE + par * 48 * 256;
#pragma unroll
        for (int it = 0; it < 3; ++it) {
            const int j   = it * 512 + tid;      // [0,1536)
            const int row = j >> 5;              // [0,48)
            const int ofs = (row * 256 + (j & 31) * 8) ^ ((row & 7) << 3);
            *(bf16x8*)&Bsh[ofs] = *(const bf16x8*)(src + j * 8);
        }
    }
    __syncthreads();                             // the ONLY block-wide barrier

    const bool v0 = (n >= 10), v3 = (n < 10);
    const int r0 = v0 ? (n - 10) : 0;
    const int r1 = n + 6;
    const int r2 = n + 22;
    const int r3 = v3 ? (n + 38) : 0;            // all in [0,48)

#pragma unroll
    for (int p = 0; p < 3; ++p) {
        const int dyp = p * 8 + slot;
        const int y   = y2 + 20 - 2 * dyp;
        const bool live = (dyp < 21) && (y >= 0) && (y < 64);
        if (!live) continue;                     // wave-uniform

        f32x4 acc[9];
#pragma unroll
        for (int t2 = 0; t2 < 9; ++t2) acc[t2] = (f32x4)0.0f;

        // Per-lane A base; (Xi,ks) offset = Xi*4096 + ks*32 shorts.
        const short* Ap = Ag + ((size_t)(b * 64 + y) * 96 + par * 48) * 256
                        + n * 256 + q * 8;

        bf16x8 a0[3], a1[3], a2[3], a3[3];
#define LOADA(buf, ks) \
        buf[0] = *(const bf16x8*)(Ap + 0 * 4096 + (ks) * 32); \
        buf[1] = *(const bf16x8*)(Ap + 1 * 4096 + (ks) * 32); \
        buf[2] = *(const bf16x8*)(Ap + 2 * 4096 + (ks) * 32);

        LOADA(a0, 0) LOADA(a1, 1) LOADA(a2, 2) LOADA(a3, 3)

#define STEP(ks, ab, PF) { \
        const int ko = (ks) * 32 + q * 8; \
        bf16x8 b0 = *(const bf16x8*)&Bsh[(r0 * 256 + ko) ^ ((r0 & 7) << 3)]; if (!v0) b0 = 0; \
        bf16x8 b1 = *(const bf16x8*)&Bsh[(r1 * 256 + ko) ^ ((r1 & 7) << 3)]; \
        bf16x8 b2 = *(const bf16x8*)&Bsh[(r2 * 256 + ko) ^ ((r2 & 7) << 3)]; \
        bf16x8 b3 = *(const bf16x8*)&Bsh[(r3 * 256 + ko) ^ ((r3 & 7) << 3)]; if (!v3) b3 = 0; \
        acc[0] = __builtin_amdgcn_mfma_f32_16x16x32_bf16(ab[0], b0, acc[0], 0, 0, 0); \
        acc[1] = __builtin_amdgcn_mfma_f32_16x16x32_bf16(ab[0], b1, acc[1], 0, 0, 0); \
        acc[2] = __builtin_amdgcn_mfma_f32_16x16x32_bf16(ab[0], b2, acc[2], 0, 0, 0); \
        acc[3] = __builtin_amdgcn_mfma_f32_16x16x32_bf16(ab[1], b1, acc[3], 0, 0, 0); \
        acc[4] = __builtin_amdgcn_mfma_f32_16x16x32_bf16(ab[1], b2, acc[4], 0, 0, 0); \
        acc[5] = __builtin_amdgcn_mfma_f32_16x16x32_bf16(ab[1], b3, acc[5], 0, 0, 0); \
        acc[6] = __builtin_amdgcn_mfma_f32_16x16x32_bf16(ab[2], b2, acc[6], 0, 0, 0); \
        acc[7] = __builtin_amdgcn_mfma_f32_16x16x32_bf16(ab[2], b3, acc[7], 0, 0, 0); \
        if (PF) { LOADA(ab, (ks) + 4) } \
    }
        // acc[8] (X2,U4): B cols OOB -> zeros; its in-band (k,xe) are true-zero
        // outputs and MUST still be stored (coverage of all 1008 per round).

        STEP(0, a0, 1) STEP(1, a1, 1) STEP(2, a2, 1) STEP(3, a3, 1)
        STEP(4, a0, 0) STEP(5, a1, 0) STEP(6, a2, 0) STEP(7, a3, 0)
#undef STEP
#undef LOADA

        // Direct epilogue: lane stores its own 36 C-elements, predicated k<21.
        // (k,xe) <-> output element is 1:1 across tiles; union covers all
        // xe in [0,48) x k in [0,21) exactly once (same set scr covered).
        const size_t obase = ((size_t)(b * 441 + dyp * 21) * 64 + y) * 96 + par;
        const int mb = q * 4;
#pragma unroll
        for (int t2 = 0; t2 < 9; ++t2) {
            const int Xi = (t2 < 3) ? 0 : (t2 < 6 ? 1 : 2);
            constexpr int UJ[9] = {0, 1, 2, 1, 2, 3, 2, 3, 4};
            const int ub = UJ[t2] * 16;
#pragma unroll
            for (int rr = 0; rr < 4; ++rr) {
                const int xe = Xi * 16 + mb + rr;
                const int k  = ub + n - xe;
                if ((unsigned)k < 21u)
                    out[obase + (size_t)k * 6144 + 2 * xe] = acc[t2][rr] * (1.0f / 256.0f);
            }
        }
    }
}

extern "C" void kernel_launch(void* const* d_in, const int* in_sizes, int n_in,
                              void* d_out, int out_size, void* d_ws, size_t ws_size,
                              hipStream_t stream) {
    const float* in1 = (const float*)d_in[0];
    const float* in2 = (const float*)d_in[1];
    float* out = (float*)d_out;

    short* Ag = (short*)d_ws;                    // 256 planes * 24576 shorts = 12.58 MB
    short* Bg = Ag + (size_t)256 * PLANE;        // 12.58 MB

    corr_prepass<<<dim3(512), dim3(512), 0, stream>>>(in1, in2, Ag, Bg);
    corr_mfma<<<dim3(512), dim3(512), 0, stream>>>(Ag, Bg, out);
}

// Round 17
// 133.445 us; speedup vs baseline: 1.1123x; 1.1123x over previous
//
#include <hip/hip_runtime.h>

// Correlation via bf16 MFMA banded Gram.
// out[b, dyp*21+k, y, x] = (1/256) * sum_c in1[b,c,y,x] * in2[b,c,y+2(dyp-10), x+2(k-10)]
// Layouts (workspace): Ag/Bg[b*64+y][par*48+col][c] bf16, x = 2*col+par.
//
// R23 = R21 verbatim (session best, 133.76us). R22 proved the scr epilogue is
// a WIN (+13us store-issue efficiency) and that 28% occupancy is the grid's
// natural TLP ceiling. Falsified levers: barriers (R9), A-ILP (R11/R13/R18),
// TLP capacity (R19/R22), request-halving (R21 ~2%), epilogue removal (R22).
// Ledger: 86us harness ws-fill (untouchable) + ~7us prepass (HBM-BW-bound)
// + ~41us main (no pipe >30%, all levers tested) = ~134us structural floor.
//
// Structure: 512-thr/8-wave/same-par blocks, grid 512; pairing identity
// (2m,z),(2m+1,z+2) share A row; Bsh[2] XOR-swizzled; wave-private scr with
// 2 k-passes; XCD chunk = (b, z-half) with par in dispatch bit0 (store merge).

typedef short bf16x8 __attribute__((ext_vector_type(8)));
typedef float f32x4  __attribute__((ext_vector_type(4)));

#define PLANE 24576         // shorts per (b,y) plane: 96 rows * 256 c
#define ST    40            // prepass LDS row stride (shorts)

__device__ __forceinline__ short f2bf(float f) {
    union { float f; unsigned u; } x; x.f = f;
    const unsigned u = x.u;
    return (short)((u + 0x7fffu + ((u >> 16) & 1u)) >> 16);
}

// ---------- prepass: fp32 [b][c][y][x] -> bf16 [b*64+y][par*48+col][c] ----------
__global__ __launch_bounds__(512)
void corr_prepass(const float* __restrict__ in1, const float* __restrict__ in2,
                  short* __restrict__ dstA, short* __restrict__ dstB) {
    const int bid = blockIdx.x;
    const int sel = bid >> 8;
    const int r   = bid & 255;
    const int b   = r >> 6;
    const int yt  = (r >> 3) & 7;
    const int ct  = r & 7;
    const int c0 = ct * 32, y0 = yt * 8;
    const float* src = sel ? in2 : in1;
    short* dst = sel ? dstB : dstA;

    __shared__ __align__(16) short T[768 * ST];   // [xx = yy*96+x][32c], 61.4 KB
    const int tid = threadIdx.x;

#pragma unroll
    for (int it = 0; it < 2; ++it) {
        const int d = it * 512 + tid;            // [0,1024), use d<768
        if (d < 768) {
            const int g = d / 192;
            const int f = d - g * 192;
            float4 v[8];
#pragma unroll
            for (int j = 0; j < 8; ++j) {
                const int c = c0 + g * 8 + j;
                v[j] = *(const float4*)(src + ((size_t)(b * 256 + c) * 64 + y0) * 96 + 4 * f);
            }
            bf16x8 w0, w1, w2, w3;
#pragma unroll
            for (int j = 0; j < 8; ++j) {
                w0[j] = f2bf(v[j].x); w1[j] = f2bf(v[j].y);
                w2[j] = f2bf(v[j].z); w3[j] = f2bf(v[j].w);
            }
            const int perm = ((g ^ (f & 3)) * 8);
            const int base = 4 * f * ST + perm;
            *(bf16x8*)&T[base]          = w0;
            *(bf16x8*)&T[base + ST]     = w1;
            *(bf16x8*)&T[base + 2*ST]   = w2;
            *(bf16x8*)&T[base + 3*ST]   = w3;
        }
    }
    __syncthreads();

#pragma unroll
    for (int it = 0; it < 6; ++it) {
        const int D  = it * 512 + tid;           // [0,3072)
        const int Rl = D >> 2, gp = D & 3;
        const int yy  = Rl / 96;
        const int rl  = Rl - yy * 96;
        const int par = rl / 48;
        const int col = rl - par * 48;
        const int x   = 2 * col + par;
        const int xx  = yy * 96 + x;
        const int perm = ((gp ^ ((xx >> 2) & 3)) * 8);
        const bf16x8 w = *(const bf16x8*)&T[xx * ST + perm];
        const size_t Rg = (size_t)(b * 64 + y0 + yy) * 96 + par * 48 + col;
        *(bf16x8*)(dst + Rg * 256 + c0 + gp * 8) = w;
    }
}

#define MFMA16(A, B, C) __builtin_amdgcn_mfma_f32_16x16x32_bf16(A, B, C, 0, 0, 0)

// ---------- main kernel: 512 thr = 8 waves, same par; wave pairs (2m,z),(2m+1,z+2) ----------
__global__ __launch_bounds__(512, 2)
void corr_mfma(const short* __restrict__ Ag, const short* __restrict__ Bg,
               float* __restrict__ out) {
    // XCD chunk = (b, z-half); par in dispatch bit0 (store half-line merge).
    const int bhw = blockIdx.x;                  // [0,512)
    const int bid = ((bhw & 7) << 6) | (bhw >> 3);
    const int xcd = bid >> 6;
    const int b   = xcd >> 1;
    const int zhi = xcd & 1;
    const int inner = bid & 63;
    const int par = inner & 1;
    const int z   = (zhi << 5) | (inner >> 1);   // even-set y2

    const int tid  = threadIdx.x;
    const int lane = tid & 63, slot = tid >> 6;  // slot in [0,8)
    const int n    = lane & 15, q = lane >> 4;

    __shared__ __align__(16) short Bsh[2][48 * 256]; // 49152 B, XOR-swizzled rows
    __shared__ __align__(16) float scr[8][528];      // 16896 B, per-wave

    const int y2o = (z < 62) ? (z + 2) : (z - 62);   // odd-set y2

    // stage both B half-planes (swizzle: short_idx ^= (row&7)<<3)
    {
        const short* se = Bg + (size_t)(b * 64 + z)   * PLANE + par * 48 * 256;
        const short* so = Bg + (size_t)(b * 64 + y2o) * PLANE + par * 48 * 256;
#pragma unroll
        for (int it = 0; it < 3; ++it) {
            const int j   = it * 512 + tid;      // [0,1536)
            const int row = j >> 5;
            const int ofs = (row * 256 + (j & 31) * 8) ^ ((row & 7) << 3);
            *(bf16x8*)&Bsh[0][ofs] = *(const bf16x8*)(se + j * 8);
        }
#pragma unroll
        for (int it = 0; it < 3; ++it) {
            const int j   = it * 512 + tid;
            const int row = j >> 5;
            const int ofs = (row * 256 + (j & 31) * 8) ^ ((row & 7) << 3);
            *(bf16x8*)&Bsh[1][ofs] = *(const bf16x8*)(so + j * 8);
        }
    }
    __syncthreads();                             // the ONLY block-wide barrier

    const bool v0 = (n >= 10), v3 = (n < 10);
    const int r0 = v0 ? (n - 10) : 0;
    const int r1 = n + 6;
    const int r2 = n + 22;
    const int r3 = v3 ? (n + 38) : 0;            // all in [0,48)
    float* const sc = scr[slot];

#define LOADA(buf, ks) \
    buf[0] = *(const bf16x8*)(Ap + 0 * 4096 + (ks) * 32); \
    buf[1] = *(const bf16x8*)(Ap + 1 * 4096 + (ks) * 32); \
    buf[2] = *(const bf16x8*)(Ap + 2 * 4096 + (ks) * 32);

// one ks-step: A-frag consumed TWICE back-to-back (even plane, odd plane)
#define DSTEP(ks, ab, PF) { \
    const int ko = (ks) * 32 + q * 8; \
    bf16x8 e0 = *(const bf16x8*)&Bsh[0][(r0 * 256 + ko) ^ ((r0 & 7) << 3)]; if (!v0) e0 = 0; \
    bf16x8 e1 = *(const bf16x8*)&Bsh[0][(r1 * 256 + ko) ^ ((r1 & 7) << 3)]; \
    bf16x8 e2 = *(const bf16x8*)&Bsh[0][(r2 * 256 + ko) ^ ((r2 & 7) << 3)]; \
    bf16x8 e3 = *(const bf16x8*)&Bsh[0][(r3 * 256 + ko) ^ ((r3 & 7) << 3)]; if (!v3) e3 = 0; \
    accE[0] = MFMA16(ab[0], e0, accE[0]); \
    accE[1] = MFMA16(ab[0], e1, accE[1]); \
    accE[2] = MFMA16(ab[0], e2, accE[2]); \
    accE[3] = MFMA16(ab[1], e1, accE[3]); \
    accE[4] = MFMA16(ab[1], e2, accE[4]); \
    accE[5] = MFMA16(ab[1], e3, accE[5]); \
    accE[6] = MFMA16(ab[2], e2, accE[6]); \
    accE[7] = MFMA16(ab[2], e3, accE[7]); \
    bf16x8 o0 = *(const bf16x8*)&Bsh[1][(r0 * 256 + ko) ^ ((r0 & 7) << 3)]; if (!v0) o0 = 0; \
    bf16x8 o1 = *(const bf16x8*)&Bsh[1][(r1 * 256 + ko) ^ ((r1 & 7) << 3)]; \
    bf16x8 o2 = *(const bf16x8*)&Bsh[1][(r2 * 256 + ko) ^ ((r2 & 7) << 3)]; \
    bf16x8 o3 = *(const bf16x8*)&Bsh[1][(r3 * 256 + ko) ^ ((r3 & 7) << 3)]; if (!v3) o3 = 0; \
    accO[0] = MFMA16(ab[0], o0, accO[0]); \
    accO[1] = MFMA16(ab[0], o1, accO[1]); \
    accO[2] = MFMA16(ab[0], o2, accO[2]); \
    accO[3] = MFMA16(ab[1], o1, accO[3]); \
    accO[4] = MFMA16(ab[1], o2, accO[4]); \
    accO[5] = MFMA16(ab[1], o3, accO[5]); \
    accO[6] = MFMA16(ab[2], o2, accO[6]); \
    accO[7] = MFMA16(ab[2], o3, accO[7]); \
    if (PF) { LOADA(ab, (ks) + 4) } \
}
    // acc*[8] (X2,U4) stays zero; its in-band (k,xe) outputs are true zeros.

#define EPILOG(DYP, Y, AC) { \
    const int mb = q * 4; \
    _Pragma("unroll") \
    for (int kp = 0; kp < 2; ++kp) { \
        const int k0 = kp ? 11 : 0; \
        const int kn = kp ? 10 : 11; \
        _Pragma("unroll") \
        for (int t2 = 0; t2 < 9; ++t2) { \
            const int Xi = (t2 < 3) ? 0 : (t2 < 6 ? 1 : 2); \
            constexpr int UJ[9] = {0, 1, 2, 1, 2, 3, 2, 3, 4}; \
            const int ub = UJ[t2] * 16; \
            _Pragma("unroll") \
            for (int rr = 0; rr < 4; ++rr) { \
                const int xe = Xi * 16 + mb + rr; \
                const int k  = ub + n - xe; \
                if ((unsigned)(k - k0) < (unsigned)kn) \
                    sc[xe * 11 + (k - k0)] = AC[t2][rr]; \
            } \
        } \
        const size_t ob = ((size_t)(b * 441 + (DYP) * 21 + k0) * 64 + (Y)) * 96 + par; \
        const int nit = kp ? 8 : 9; \
        _Pragma("unroll") \
        for (int it2 = 0; it2 < 9; ++it2) { \
            if (it2 < nit) { \
                const int e = it2 * 64 + lane; \
                if (e < kn * 48) { \
                    const int k  = e / 48; \
                    const int xe = e - k * 48; \
                    out[ob + (size_t)k * 6144 + 2 * xe] = sc[xe * 11 + k] * (1.0f / 256.0f); \
                } \
            } \
        } \
    } }

#pragma unroll
    for (int p = 0; p < 2; ++p) {
        const int m = p * 8 + slot;              // [0,16)
        if (m >= 11) continue;                   // wave-uniform
        const int dyp_e = 2 * m, dyp_o = 2 * m + 1;
        const int y_e = z   + 20 - 4 * m;
        const int y_o = y2o + 18 - 4 * m;        // == y_e when z < 62
        const bool live_e = (y_e >= 0) && (y_e < 64);
        const bool live_o = (m < 10) && (y_o >= 0) && (y_o < 64);
        if (!live_e && !live_o) continue;

        const int y_ld = live_e ? y_e : y_o;     // shared row (edge sets disjoint)
        const short* Ap = Ag + ((size_t)(b * 64 + y_ld) * 96 + par * 48) * 256
                        + n * 256 + q * 8;

        f32x4 accE[9], accO[9];
#pragma unroll
        for (int t = 0; t < 9; ++t) { accE[t] = (f32x4)0.0f; accO[t] = (f32x4)0.0f; }

        bf16x8 a0[3], a1[3], a2[3], a3[3];
        LOADA(a0, 0) LOADA(a1, 1) LOADA(a2, 2) LOADA(a3, 3)

        DSTEP(0, a0, 1) DSTEP(1, a1, 1) DSTEP(2, a2, 1) DSTEP(3, a3, 1)
        DSTEP(4, a0, 0) DSTEP(5, a1, 0) DSTEP(6, a2, 0) DSTEP(7, a3, 0)

        if (live_e) EPILOG(dyp_e, y_e, accE)
        if (live_o) EPILOG(dyp_o, y_o, accO)
    }
#undef DSTEP
#undef LOADA
#undef EPILOG
}

extern "C" void kernel_launch(void* const* d_in, const int* in_sizes, int n_in,
                              void* d_out, int out_size, void* d_ws, size_t ws_size,
                              hipStream_t stream) {
    const float* in1 = (const float*)d_in[0];
    const float* in2 = (const float*)d_in[1];
    float* out = (float*)d_out;

    short* Ag = (short*)d_ws;                    // 256 planes * 24576 shorts = 12.58 MB
    short* Bg = Ag + (size_t)256 * PLANE;        // 12.58 MB

    corr_prepass<<<dim3(512), dim3(512), 0, stream>>>(in1, in2, Ag, Bg);
    corr_mfma<<<dim3(512), dim3(512), 0, stream>>>(Ag, Bg, out);
}